// Round 1
// baseline (940.592 us; speedup 1.0000x reference)
//
#include <hip/hip_runtime.h>
#include <cstdint>
#include <cstddef>

// ---------- types ----------
typedef __bf16  bf16x8f __attribute__((ext_vector_type(8)));      // MFMA A/B operand (4 VGPRs)
typedef unsigned short u16x8 __attribute__((ext_vector_type(8))); // storage view of 8 bf16
typedef float   f32x16 __attribute__((ext_vector_type(16)));      // MFMA 32x32 C/D operand

__device__ __forceinline__ unsigned short f2bf(float f) {
    union { float f; uint32_t u; } c; c.f = f;
    uint32_t u = c.u;
    return (unsigned short)((u + 0x7fffu + ((u >> 16) & 1u)) >> 16);  // RNE
}

// tanh(x) = 1 - 2/(e^{2x}+1); exact at +/-inf, ~1e-6 abs err
__device__ __forceinline__ float fast_tanh(float x) {
    float e = __builtin_exp2f(2.885390081777927f * x);   // e^{2x}
    return 1.0f - 2.0f * __builtin_amdgcn_rcpf(e + 1.0f);
}

// async 16B global -> LDS (DMA; LDS dest is wave-uniform base + lane*16)
__device__ __forceinline__ void load16_lds(const void* g, unsigned short* l) {
    __builtin_amdgcn_global_load_lds(
        (const __attribute__((address_space(1))) unsigned int*)g,
        (__attribute__((address_space(3))) unsigned int*)l,
        16, 0, 0);
}

// ---------- kernel 0: detect mask storage layout ----------
__global__ __launch_bounds__(256)
void detect_mask(const unsigned char* __restrict__ m, int* __restrict__ flag) {
    __shared__ int s_gt1, s_off;
    if (threadIdx.x == 0) { s_gt1 = 0; s_off = 0; }
    __syncthreads();
    int gt1 = 0, off = 0;
    for (int k = threadIdx.x; k < 4096; k += 256) {
        unsigned char b = m[k];
        if (b > 1) gt1 = 1;
        if ((k & 3) && b) off = 1;
    }
    if (gt1) atomicOr(&s_gt1, 1);
    if (off) atomicOr(&s_off, 1);
    __syncthreads();
    if (threadIdx.x == 0) *flag = (!s_gt1 && s_off) ? 1 : 0;
}

// ---------- kernel 1: cast x fp32 -> bf16 ----------
__global__ __launch_bounds__(256)
void cast_f32_bf16(const float* __restrict__ in, unsigned short* __restrict__ out, int n) {
    int tid = blockIdx.x * blockDim.x + threadIdx.x;
    int stride = gridDim.x * blockDim.x;
    for (int e = tid * 4; e < n; e += stride * 4) {
        float4 v = *(const float4*)(in + e);
        ushort4 o;
        o.x = f2bf(v.x); o.y = f2bf(v.y); o.z = f2bf(v.z); o.w = f2bf(v.w);
        *(ushort4*)(out + e) = o;
    }
}

// ---------- kernel 2: masked weight -> bf16 ----------
__global__ __launch_bounds__(256)
void mask_cast(const float* __restrict__ w, const void* __restrict__ mv,
               const int* __restrict__ flag, unsigned short* __restrict__ out, int n) {
    const bool u8 = (*flag != 0);
    int tid = blockIdx.x * blockDim.x + threadIdx.x;
    int stride = gridDim.x * blockDim.x;
    for (int e = tid * 4; e < n; e += stride * 4) {
        float4 v = *(const float4*)(w + e);
        int m0, m1, m2, m3;
        if (u8) {
            uchar4 mm = *(const uchar4*)((const unsigned char*)mv + e);
            m0 = mm.x; m1 = mm.y; m2 = mm.z; m3 = mm.w;
        } else {
            int4 mm = ((const int4*)mv)[e >> 2];
            m0 = mm.x; m1 = mm.y; m2 = mm.z; m3 = mm.w;
        }
        ushort4 o;
        o.x = m0 ? f2bf(v.x) : (unsigned short)0;
        o.y = m1 ? f2bf(v.y) : (unsigned short)0;
        o.z = m2 ? f2bf(v.z) : (unsigned short)0;
        o.w = m3 ? f2bf(v.w) : (unsigned short)0;
        *(ushort4*)(out + e) = o;
    }
}

// ---------- GEMM: C = tanh(A[M,K] x W[N,K]^T + bias) ----------
// 256x256 tile, BK=64, 512 thr = 8 waves (2Mx4N), per-wave 128x64 out via
// mfma_f32_32x32x16_bf16 (acc[4][2] f32x16 = 128 VGPR).
// 8-phase schedule per 2 K-tiles (guide S5 template, T1+T2+T3+T4+T5):
//   phase = (nt, k-half): P1(n0,k01) P2(n1,k01) P3(n0,k23) P4(n1,k23)
//   staging units: A-k01/A-k23 (256 rows x 4 chunks), B-n0/B-n1 (128 rows x 8).
//   at tile t: P1 stages A-k23(t+1), P2 B-n1(t+1), P3 A-k01(t+2), P4 B-n0(t+2)
//   -> every stage lands >=1 end-barrier after its region's last reader (WAR ok
//      with 2 buffers), every unit staged 4-6 phases before first use (RAW via
//      counted vmcnt(4) at P4/P8 only; never 0 in main loop).
// LDS swizzle (pre-applied to GLOBAL source so global_load_lds dest stays
// linear, rule #21): A chunk c ^= (r&3) within 4-chunk rows; B chunk ^= (n&7)
// within 8-chunk rows. Both conflict-free by bank arithmetic.
// Epilogue mapping (HW-verified): C/D col=lane&31, row=(reg&3)+8*(reg>>2)+4*(lane>>5).
template <typename OutT, bool FUSE>
__global__ __launch_bounds__(512, 2)
void gemm256(const unsigned short* __restrict__ A,
             const unsigned short* __restrict__ W,
             const float* __restrict__ bias,
             OutT* __restrict__ out,
             const float* __restrict__ w1, const float* __restrict__ b1,
             const float* __restrict__ w2, const float* __restrict__ b2,
             int N, int K, int lbx) {
    // [buf(2)][ A: 2 units x 8192 | B: 2 units x 8192 ] shorts = 128 KiB
    __shared__ __align__(16) unsigned short lds[65536];

    const int t    = threadIdx.x;
    const int lane = t & 63;
    const int wave = t >> 6;
    const int l31  = lane & 31;
    const int lh   = lane >> 5;
    const int wrow = (wave >> 2) * 128;
    const int wcol = (wave & 3) * 64;

    const int id = blockIdx.x;
    const int bx = id & ((1 << lbx) - 1);   // = XCD id for lbx=3 -> W panel L2-resident
    const int by = id >> lbx;
    const int bm = by * 256, bn = bx * 256;

    const char* Au = (const char*)(A + (size_t)bm * K);
    const char* Wu = (const char*)(W + (size_t)bn * K);

    // ---- staging source byte offsets (loop-invariant, per-thread) ----
    // A unit Uk: LDS chunk u -> row r=u>>2, lds col c=u&3, global chunk Uk*4 + (c^(r&3))
    // B unit Un: LDS chunk u -> r_loc=u>>3, c=u&7; n=(r_loc&31)+((r_loc>>5)<<6)+Un*32,
    //            global chunk c^(n&7)
    uint32_t aSrc[2], bSrc[2][2];
#pragma unroll
    for (int j = 0; j < 2; ++j) {
        const int u = t + j * 512;
        { const int r = u >> 2, c = u & 3;
          aSrc[j] = (uint32_t)((r * K + ((c ^ (r & 3)) << 3)) * 2); }
        { const int rl = u >> 3, c = u & 7;
#pragma unroll
          for (int Un = 0; Un < 2; ++Un) {
              const int n = (rl & 31) + ((rl >> 5) << 6) + Un * 32;
              bSrc[Un][j] = (uint32_t)((n * K + ((c ^ (n & 7)) << 3)) * 2);
          } }
    }

    // ---- fragment read address pieces (shorts) ----
    int aRow[4];
#pragma unroll
    for (int mt = 0; mt < 4; ++mt) aRow[mt] = (wrow + mt * 32 + l31) * 32;
    int aSwz[2];
#pragma unroll
    for (int j = 0; j < 2; ++j) aSwz[j] = ((j * 2 + lh) ^ (l31 & 3)) << 3;
    int bBase[2];
#pragma unroll
    for (int nt = 0; nt < 2; ++nt)
        bBase[nt] = 16384 + ((((wcol >> 5) + nt) & 1) * 8192)
                  + (((wcol + nt * 32) >> 6) * 2048) + l31 * 64;
    int bSwz[4];
#pragma unroll
    for (int kp = 0; kp < 2; ++kp)
#pragma unroll
        for (int j = 0; j < 2; ++j)
            bSwz[kp * 2 + j] = ((kp * 4 + j * 2 + lh) ^ (l31 & 7)) << 3;

#define STAGE_A(buf, Uk, kB) do {                                              \
    const char* g_ = Au + (kB);                                                \
    unsigned short* l_ = lds + (buf) * 32768 + (Uk) * 8192 + t * 8;            \
    load16_lds(g_ + aSrc[0] + (Uk) * 64, l_);                                  \
    load16_lds(g_ + aSrc[1] + (Uk) * 64, l_ + 4096);                           \
} while (0)

#define STAGE_B(buf, Un, kB) do {                                              \
    const char* g_ = Wu + (kB);                                                \
    unsigned short* l_ = lds + (buf) * 32768 + 16384 + (Un) * 8192 + t * 8;    \
    load16_lds(g_ + bSrc[Un][0], l_);                                          \
    load16_lds(g_ + bSrc[Un][1], l_ + 4096);                                   \
} while (0)

#define BAR    asm volatile("s_barrier" ::: "memory")
#define VM4BAR do { asm volatile("s_waitcnt vmcnt(4)" ::: "memory"); BAR; } while (0)

// one phase: 10 ds_read_b128 || 1 half-unit stage issue -> bar -> 8 MFMA (prio 1)
#define PHASE(buf, nt, kp, STAGE_STMT) do {                                    \
    u16x8 aF[4][2], bF[2];                                                     \
    const unsigned short* Lb_ = lds + (buf) * 32768;                           \
    _Pragma("unroll")                                                          \
    for (int j_ = 0; j_ < 2; ++j_) {                                           \
        _Pragma("unroll")                                                      \
        for (int mt_ = 0; mt_ < 4; ++mt_)                                      \
            aF[mt_][j_] = *(const u16x8*)(Lb_ + (kp) * 8192 + aRow[mt_] + aSwz[j_]); \
        bF[j_] = *(const u16x8*)(Lb_ + bBase[nt] + bSwz[(kp) * 2 + j_]);       \
    }                                                                          \
    STAGE_STMT;                                                                \
    BAR;                                                                       \
    __builtin_amdgcn_s_setprio(1);                                             \
    _Pragma("unroll")                                                          \
    for (int j_ = 0; j_ < 2; ++j_)                                             \
        _Pragma("unroll")                                                      \
        for (int mt_ = 0; mt_ < 4; ++mt_)                                      \
            acc[mt_][nt] = __builtin_amdgcn_mfma_f32_32x32x16_bf16(            \
                __builtin_bit_cast(bf16x8f, aF[mt_][j_]),                      \
                __builtin_bit_cast(bf16x8f, bF[j_]), acc[mt_][nt], 0, 0, 0);   \
    __builtin_amdgcn_s_setprio(0);                                             \
} while (0)

    f32x16 acc[4][2] = {};

    // prologue: tile0 all 4 units, tile1 A-k01 + B-n0 (12 loads); wait tile0
    STAGE_A(0, 0, 0); STAGE_A(0, 1, 0); STAGE_B(0, 0, 0); STAGE_B(0, 1, 0);
    STAGE_A(1, 0, 128); STAGE_B(1, 0, 128);
    asm volatile("s_waitcnt vmcnt(4)" ::: "memory");
    BAR;

    const int KB = K * 2;        // bytes; one K-tile = 128 B
    const int KL = KB - 128;     // last tile byte offset (stage clamp)
    for (int k0 = 0; k0 < KB; k0 += 256) {
        const int kA = k0 + 128;                       // tile o (always valid)
        int kB1 = k0 + 256; if (kB1 > KL) kB1 = KL;    // tile e+2 (clamped)
        int kB2 = k0 + 384; if (kB2 > KL) kB2 = KL;    // tile e+3 (clamped)
        // tile e (buf0)
        PHASE(0, 0, 0, STAGE_A(1, 1, kA));  BAR;       // stage A-k23(o)
        PHASE(0, 1, 0, STAGE_B(1, 1, kA));  BAR;       // stage B-n1(o)
        PHASE(0, 0, 1, STAGE_A(0, 0, kB1)); BAR;       // stage A-k01(e+2)
        PHASE(0, 1, 1, STAGE_B(0, 0, kB1)); VM4BAR;    // stage B-n0(e+2); tile o ready
        // tile o (buf1)
        PHASE(1, 0, 0, STAGE_A(0, 1, kB1)); BAR;       // stage A-k23(e+2)
        PHASE(1, 1, 0, STAGE_B(0, 1, kB1)); BAR;       // stage B-n1(e+2)
        PHASE(1, 0, 1, STAGE_A(1, 0, kB2)); BAR;       // stage A-k01(e+3)
        PHASE(1, 1, 1, STAGE_B(1, 0, kB2)); VM4BAR;    // stage B-n0(e+3); tile e+2 ready
    }
    // drain DMA before LDS dealloc (next block on this CU reuses our LDS)
    asm volatile("s_waitcnt vmcnt(0)" ::: "memory");

    // ---- epilogue ----
    float w10 = 0, w11 = 0, bb1 = 0, w20 = 0, w21 = 0, bb2 = 0;
    if constexpr (FUSE) {
        w10 = w1[0]; w11 = w1[1]; bb1 = b1[0];
        w20 = w2[0]; w21 = w2[1]; bb2 = b2[0];
    }
#pragma unroll
    for (int nt = 0; nt < 2; ++nt) {
        const int gn = bn + wcol + nt * 32 + l31;
        const float bv = bias[gn];
#pragma unroll
        for (int mt = 0; mt < 4; ++mt) {
#pragma unroll
            for (int reg = 0; reg < 16; ++reg) {
                const int gm = bm + wrow + mt * 32 + (reg & 3) + 8 * (reg >> 2) + 4 * lh;
                float c = fast_tanh(acc[mt][nt][reg] + bv);
                if constexpr (FUSE) {
                    float c1 = __shfl_xor(c, 1);
                    float c2 = __shfl_xor(c, 2);
                    float c3 = __shfl_xor(c, 3);
                    float y10 = fast_tanh(w10 * c  + w11 * c1 + bb1);
                    float y11 = fast_tanh(w10 * c2 + w11 * c3 + bb1);
                    float y   = fast_tanh(w20 * y10 + w21 * y11 + bb2);
                    if ((lane & 3) == 0)
                        out[(size_t)gm * (N >> 2) + (gn >> 2)] = (OutT)y;
                } else {
                    out[(size_t)gm * N + gn] = (OutT)f2bf(c);
                }
            }
        }
    }
#undef STAGE_A
#undef STAGE_B
#undef BAR
#undef VM4BAR
#undef PHASE
}

// ---------- launch ----------
extern "C" void kernel_launch(void* const* d_in, const int* in_sizes, int n_in,
                              void* d_out, int out_size, void* d_ws, size_t ws_size,
                              hipStream_t stream) {
    constexpr int B   = 16384;
    constexpr int IN  = 4096;
    constexpr int HID = 2048;
    constexpr int CNV = 1024;

    const float* x       = (const float*)d_in[0];
    const void*  mask_ih = d_in[1];
    const void*  mask_hc = d_in[2];
    const float* w_ih    = (const float*)d_in[3];
    const float* b_ih    = (const float*)d_in[4];
    const float* w_hc    = (const float*)d_in[5];
    const float* b_hc    = (const float*)d_in[6];
    const float* w_c1    = (const float*)d_in[7];
    const float* b_c1    = (const float*)d_in[8];
    const float* w_c2    = (const float*)d_in[9];
    const float* b_c2    = (const float*)d_in[10];
    float* out = (float*)d_out;

    // workspace layout (bytes)
    char* ws = (char*)d_ws;
    unsigned short* Xb  = (unsigned short*)(ws);                    // B*IN  bf16
    unsigned short* Wih = (unsigned short*)(ws + 134217728);        // HID*IN bf16
    unsigned short* Whc = (unsigned short*)(ws + 150994944);        // CNV*HID bf16
    unsigned short* Hb  = (unsigned short*)(ws + 155189248);        // B*HID bf16
    int*            flag = (int*)(ws + 222298112);

    detect_mask<<<1, 256, 0, stream>>>((const unsigned char*)mask_ih, flag);

    cast_f32_bf16<<<4096, 256, 0, stream>>>(x, Xb, B * IN);
    mask_cast<<<1024, 256, 0, stream>>>(w_ih, mask_ih, flag, Wih, HID * IN);
    mask_cast<<<256, 256, 0, stream>>>(w_hc, mask_hc, flag, Whc, CNV * HID);

    // GEMM1: [16384,4096] x [2048,4096]^T -> bf16 h ; 64x8 tiles -> 512 blocks,
    // lbx=3: bx == XCD -> each XCD's 2 MB W panel stays L2-resident.
    gemm256<unsigned short, false><<<512, 512, 0, stream>>>(
        Xb, Wih, b_ih, Hb, nullptr, nullptr, nullptr, nullptr, HID, IN, 3);

    // GEMM2 + fused double conv: [16384,2048] x [1024,2048]^T -> fp32 [16384,256]
    // 64x4 tiles -> 256 blocks (exactly 1 per CU), lbx=2.
    gemm256<float, true><<<256, 512, 0, stream>>>(
        Hb, Whc, b_hc, out, w_c1, b_c1, w_c2, b_c2, CNV, HID, 2);
}

// Round 2
// 790.223 us; speedup vs baseline: 1.1903x; 1.1903x over previous
//
#include <hip/hip_runtime.h>
#include <cstdint>
#include <cstddef>

// ---------- types ----------
typedef __bf16  bf16x8f __attribute__((ext_vector_type(8)));      // MFMA A/B operand (4 VGPRs)
typedef unsigned short u16x8 __attribute__((ext_vector_type(8))); // storage view of 8 bf16
typedef float   f32x16 __attribute__((ext_vector_type(16)));      // MFMA 32x32 C/D operand

__device__ __forceinline__ unsigned short f2bf(float f) {
    union { float f; uint32_t u; } c; c.f = f;
    uint32_t u = c.u;
    return (unsigned short)((u + 0x7fffu + ((u >> 16) & 1u)) >> 16);  // RNE
}

// tanh(x) = 1 - 2/(e^{2x}+1); exact at +/-inf, ~1e-6 abs err
__device__ __forceinline__ float fast_tanh(float x) {
    float e = __builtin_exp2f(2.885390081777927f * x);   // e^{2x}
    return 1.0f - 2.0f * __builtin_amdgcn_rcpf(e + 1.0f);
}

// async 16B global -> LDS (DMA; LDS dest is wave-uniform base + lane*16)
__device__ __forceinline__ void load16_lds(const void* g, unsigned short* l) {
    __builtin_amdgcn_global_load_lds(
        (const __attribute__((address_space(1))) unsigned int*)g,
        (__attribute__((address_space(3))) unsigned int*)l,
        16, 0, 0);
}

// ---------- kernel 0: detect mask storage layout ----------
__global__ __launch_bounds__(256)
void detect_mask(const unsigned char* __restrict__ m, int* __restrict__ flag) {
    __shared__ int s_gt1, s_off;
    if (threadIdx.x == 0) { s_gt1 = 0; s_off = 0; }
    __syncthreads();
    int gt1 = 0, off = 0;
    for (int k = threadIdx.x; k < 4096; k += 256) {
        unsigned char b = m[k];
        if (b > 1) gt1 = 1;
        if ((k & 3) && b) off = 1;
    }
    if (gt1) atomicOr(&s_gt1, 1);
    if (off) atomicOr(&s_off, 1);
    __syncthreads();
    if (threadIdx.x == 0) *flag = (!s_gt1 && s_off) ? 1 : 0;
}

// ---------- kernel 1: cast x fp32 -> bf16 ----------
__global__ __launch_bounds__(256)
void cast_f32_bf16(const float* __restrict__ in, unsigned short* __restrict__ out, int n) {
    int tid = blockIdx.x * blockDim.x + threadIdx.x;
    int stride = gridDim.x * blockDim.x;
    for (int e = tid * 4; e < n; e += stride * 4) {
        float4 v = *(const float4*)(in + e);
        ushort4 o;
        o.x = f2bf(v.x); o.y = f2bf(v.y); o.z = f2bf(v.z); o.w = f2bf(v.w);
        *(ushort4*)(out + e) = o;
    }
}

// ---------- kernel 2: masked weight -> bf16 ----------
__global__ __launch_bounds__(256)
void mask_cast(const float* __restrict__ w, const void* __restrict__ mv,
               const int* __restrict__ flag, unsigned short* __restrict__ out, int n) {
    const bool u8 = (*flag != 0);
    int tid = blockIdx.x * blockDim.x + threadIdx.x;
    int stride = gridDim.x * blockDim.x;
    for (int e = tid * 4; e < n; e += stride * 4) {
        float4 v = *(const float4*)(w + e);
        int m0, m1, m2, m3;
        if (u8) {
            uchar4 mm = *(const uchar4*)((const unsigned char*)mv + e);
            m0 = mm.x; m1 = mm.y; m2 = mm.z; m3 = mm.w;
        } else {
            int4 mm = ((const int4*)mv)[e >> 2];
            m0 = mm.x; m1 = mm.y; m2 = mm.z; m3 = mm.w;
        }
        ushort4 o;
        o.x = m0 ? f2bf(v.x) : (unsigned short)0;
        o.y = m1 ? f2bf(v.y) : (unsigned short)0;
        o.z = m2 ? f2bf(v.z) : (unsigned short)0;
        o.w = m3 ? f2bf(v.w) : (unsigned short)0;
        *(ushort4*)(out + e) = o;
    }
}

// ---------- GEMM: C = tanh(A[M,K] x W[N,K]^T + bias) ----------
// 256x256 tile, BK=64, 512 thr = 8 waves (2Mx4N), per-wave 128x64 out via
// mfma_f32_32x32x16_bf16 (acc[4][2] f32x16).
// Phase = (buf, kp): reads 8 A-frags + 4 B-frags (12 ds_read_b128, each A frag
// used for BOTH nt -> 24 reads/wave/K-tile, the minimum), 16 MFMA.
// 4 phases per iteration (2 K-tiles: e=2t in buf0, o=2t+1 in buf1). Staging
// (2 units = 4 global_load_lds per phase):
//   P1: a23(o),b0(o)->buf1   P2: b1(o)->buf1, a01(e+2)->buf0
//   P3: a23(e+2),b0(e+2)->buf0   P4: b1(e+2)->buf0, a01(o+2)->buf1
// WAR: every stage lands >=1 end-barrier after its region's last reader.
// RAW: counted s_waitcnt vmcnt(2) + s_barrier at end-P2 and end-P4 only
// (b1 staged before a01 in P2/P4, so the 2 allowed-outstanding are always the
// not-yet-needed a01 loads). Never vmcnt(0) in the main loop.
// LDS bank swizzle (pre-applied to GLOBAL source so the linear-dest
// global_load_lds stays legal, rule #21):
//   A rows = 64 B (4 chunks): chunk ^= (row>>1)&3 -> rows 0..7 hit all 8
//     windows (2 parity x 4 chunk); quarter-wave reads are 2-way max (free).
//   B rows = 128 B (8 chunks): chunk ^= n&7 -> quarter-wave 2-way max.
// XCD map: by in low 3 bits (same-A-panel blocks -> same XCD, measured-good
// in the 270 MB-fetch r0 kernel); bx in mid bits.
// Epilogue mapping (HW-verified): col=lane&31, row=(reg&3)+8*(reg>>2)+4*(lane>>5).
template <typename OutT, bool FUSE>
__global__ __launch_bounds__(512, 2)
void gemm256(const unsigned short* __restrict__ A,
             const unsigned short* __restrict__ W,
             const float* __restrict__ bias,
             OutT* __restrict__ out,
             const float* __restrict__ w1, const float* __restrict__ b1,
             const float* __restrict__ w2, const float* __restrict__ b2,
             int N, int K, int lbx) {
    // [buf(2)][ A: 2 units x 8192 | B: 2 units x 8192 ] shorts = 128 KiB
    __shared__ __align__(16) unsigned short lds[65536];

    const int t    = threadIdx.x;
    const int lane = t & 63;
    const int wave = t >> 6;
    const int l31  = lane & 31;
    const int lh   = lane >> 5;
    const int wrow = (wave >> 2) * 128;
    const int wcol = (wave & 3) * 64;

    const int id = blockIdx.x;
    const int bx = (id >> 3) & ((1 << lbx) - 1);
    const int by = (id & 7) | ((id >> (3 + lbx)) << 3);
    const int bm = by * 256, bn = bx * 256;

    const char* Au = (const char*)(A + (size_t)bm * K);
    const char* Wu = (const char*)(W + (size_t)bn * K);

    // ---- staging source byte offsets (loop-invariant, per-thread) ----
    // A unit Uk: LDS chunk u -> row r=u>>2, lds chunk c=u&3,
    //            global chunk Uk*4 + (c ^ ((r>>1)&3))
    // B unit Un: LDS chunk u -> rl=u>>3, c=u&7; n=(rl&31)+((rl>>5)<<6)+Un*32,
    //            global chunk c ^ (n&7)
    uint32_t aSrc[2], bSrc[2][2];
#pragma unroll
    for (int j = 0; j < 2; ++j) {
        const int u = t + j * 512;
        { const int r = u >> 2, c = u & 3;
          aSrc[j] = (uint32_t)((r * K + ((c ^ ((r >> 1) & 3)) << 3)) * 2); }
        { const int rl = u >> 3, c = u & 7;
#pragma unroll
          for (int Un = 0; Un < 2; ++Un) {
              const int n = (rl & 31) + ((rl >> 5) << 6) + Un * 32;
              bSrc[Un][j] = (uint32_t)((n * K + ((c ^ (n & 7)) << 3)) * 2);
          } }
    }

    // ---- fragment read address pieces (shorts) ----
    int aRow[4];
#pragma unroll
    for (int mt = 0; mt < 4; ++mt) aRow[mt] = (wrow + mt * 32 + l31) * 32;
    int aSwz[2];
#pragma unroll
    for (int j = 0; j < 2; ++j) aSwz[j] = ((j * 2 + lh) ^ ((l31 >> 1) & 3)) << 3;
    int bBase[2];
#pragma unroll
    for (int nt = 0; nt < 2; ++nt)
        bBase[nt] = 16384 + ((((wcol >> 5) + nt) & 1) * 8192)
                  + (((wcol + nt * 32) >> 6) * 2048) + l31 * 64;
    int bSwz[4];
#pragma unroll
    for (int kp = 0; kp < 2; ++kp)
#pragma unroll
        for (int j = 0; j < 2; ++j)
            bSwz[kp * 2 + j] = ((kp * 4 + j * 2 + lh) ^ (l31 & 7)) << 3;

#define STAGE_A(buf, Uk, kB) do {                                              \
    const char* g_ = Au + (kB);                                                \
    unsigned short* l_ = lds + (buf) * 32768 + (Uk) * 8192 + t * 8;            \
    load16_lds(g_ + aSrc[0] + (Uk) * 64, l_);                                  \
    load16_lds(g_ + aSrc[1] + (Uk) * 64, l_ + 4096);                           \
} while (0)

#define STAGE_B(buf, Un, kB) do {                                              \
    const char* g_ = Wu + (kB);                                                \
    unsigned short* l_ = lds + (buf) * 32768 + 16384 + (Un) * 8192 + t * 8;    \
    load16_lds(g_ + bSrc[Un][0], l_);                                          \
    load16_lds(g_ + bSrc[Un][1], l_ + 4096);                                   \
} while (0)

#define BAR    asm volatile("s_barrier" ::: "memory")
#define VM2BAR do { asm volatile("s_waitcnt vmcnt(2)" ::: "memory"); BAR; } while (0)

// one phase: 12 ds_read_b128 || 2 stage units -> bar -> 16 MFMA (prio 1)
#define PHASE(buf, kp, STAGE_STMT) do {                                        \
    u16x8 aF[4][2], bF[2][2];                                                  \
    const unsigned short* Lb_ = lds + (buf) * 32768;                           \
    _Pragma("unroll")                                                          \
    for (int j_ = 0; j_ < 2; ++j_) {                                           \
        _Pragma("unroll")                                                      \
        for (int mt_ = 0; mt_ < 4; ++mt_)                                      \
            aF[mt_][j_] = *(const u16x8*)(Lb_ + (kp) * 8192 + aRow[mt_] + aSwz[j_]); \
        _Pragma("unroll")                                                      \
        for (int nt_ = 0; nt_ < 2; ++nt_)                                      \
            bF[nt_][j_] = *(const u16x8*)(Lb_ + bBase[nt_] + bSwz[(kp) * 2 + j_]); \
    }                                                                          \
    STAGE_STMT;                                                                \
    BAR;                                                                       \
    __builtin_amdgcn_s_setprio(1);                                             \
    _Pragma("unroll")                                                          \
    for (int j_ = 0; j_ < 2; ++j_)                                             \
        _Pragma("unroll")                                                      \
        for (int mt_ = 0; mt_ < 4; ++mt_)                                      \
            _Pragma("unroll")                                                  \
            for (int nt_ = 0; nt_ < 2; ++nt_)                                  \
                acc[mt_][nt_] = __builtin_amdgcn_mfma_f32_32x32x16_bf16(       \
                    __builtin_bit_cast(bf16x8f, aF[mt_][j_]),                  \
                    __builtin_bit_cast(bf16x8f, bF[nt_][j_]),                  \
                    acc[mt_][nt_], 0, 0, 0);                                   \
    __builtin_amdgcn_s_setprio(0);                                             \
} while (0)

    f32x16 acc[4][2] = {};

    // prologue: buf0 tile0 (4 units) + buf1 a01(tile1); retire tile0, leave a01
    STAGE_A(0, 0, 0); STAGE_A(0, 1, 0); STAGE_B(0, 0, 0); STAGE_B(0, 1, 0);
    STAGE_A(1, 0, 128);
    asm volatile("s_waitcnt vmcnt(2)" ::: "memory");
    BAR;

    const int KB = K * 2;        // bytes; one K-tile = 128 B
    const int KL = KB - 128;     // last-tile byte offset (stage clamp)
    for (int k0 = 0; k0 < KB; k0 += 256) {
        const int kO = k0 + 128;                       // tile o (always valid)
        int kE2 = k0 + 256; if (kE2 > KL) kE2 = KL;    // tile e+2 (clamped)
        int kO2 = k0 + 384; if (kO2 > KL) kO2 = KL;    // tile o+2 (clamped)
        PHASE(0, 0, STAGE_A(1, 1, kO);  STAGE_B(1, 0, kO));  BAR;     // P1
        PHASE(0, 1, STAGE_B(1, 1, kO);  STAGE_A(0, 0, kE2)); VM2BAR;  // P2
        PHASE(1, 0, STAGE_A(0, 1, kE2); STAGE_B(0, 0, kE2)); BAR;     // P3
        PHASE(1, 1, STAGE_B(0, 1, kE2); STAGE_A(1, 0, kO2)); VM2BAR;  // P4
    }
    // drain DMA before LDS dealloc (next block on this CU reuses our LDS)
    asm volatile("s_waitcnt vmcnt(0)" ::: "memory");

    // ---- epilogue ----
    float w10 = 0, w11 = 0, bb1 = 0, w20 = 0, w21 = 0, bb2 = 0;
    if constexpr (FUSE) {
        w10 = w1[0]; w11 = w1[1]; bb1 = b1[0];
        w20 = w2[0]; w21 = w2[1]; bb2 = b2[0];
    }
#pragma unroll
    for (int nt = 0; nt < 2; ++nt) {
        const int gn = bn + wcol + nt * 32 + l31;
        const float bv = bias[gn];
#pragma unroll
        for (int mt = 0; mt < 4; ++mt) {
#pragma unroll
            for (int reg = 0; reg < 16; ++reg) {
                const int gm = bm + wrow + mt * 32 + (reg & 3) + 8 * (reg >> 2) + 4 * lh;
                float c = fast_tanh(acc[mt][nt][reg] + bv);
                if constexpr (FUSE) {
                    float c1 = __shfl_xor(c, 1);
                    float c2 = __shfl_xor(c, 2);
                    float c3 = __shfl_xor(c, 3);
                    float y10 = fast_tanh(w10 * c  + w11 * c1 + bb1);
                    float y11 = fast_tanh(w10 * c2 + w11 * c3 + bb1);
                    float y   = fast_tanh(w20 * y10 + w21 * y11 + bb2);
                    if ((lane & 3) == 0)
                        out[(size_t)gm * (N >> 2) + (gn >> 2)] = (OutT)y;
                } else {
                    out[(size_t)gm * N + gn] = (OutT)f2bf(c);
                }
            }
        }
    }
#undef STAGE_A
#undef STAGE_B
#undef BAR
#undef VM2BAR
#undef PHASE
}

// ---------- launch ----------
extern "C" void kernel_launch(void* const* d_in, const int* in_sizes, int n_in,
                              void* d_out, int out_size, void* d_ws, size_t ws_size,
                              hipStream_t stream) {
    constexpr int B   = 16384;
    constexpr int IN  = 4096;
    constexpr int HID = 2048;
    constexpr int CNV = 1024;

    const float* x       = (const float*)d_in[0];
    const void*  mask_ih = d_in[1];
    const void*  mask_hc = d_in[2];
    const float* w_ih    = (const float*)d_in[3];
    const float* b_ih    = (const float*)d_in[4];
    const float* w_hc    = (const float*)d_in[5];
    const float* b_hc    = (const float*)d_in[6];
    const float* w_c1    = (const float*)d_in[7];
    const float* b_c1    = (const float*)d_in[8];
    const float* w_c2    = (const float*)d_in[9];
    const float* b_c2    = (const float*)d_in[10];
    float* out = (float*)d_out;

    // workspace layout (bytes)
    char* ws = (char*)d_ws;
    unsigned short* Xb  = (unsigned short*)(ws);                    // B*IN  bf16
    unsigned short* Wih = (unsigned short*)(ws + 134217728);        // HID*IN bf16
    unsigned short* Whc = (unsigned short*)(ws + 150994944);        // CNV*HID bf16
    unsigned short* Hb  = (unsigned short*)(ws + 155189248);        // B*HID bf16
    int*            flag = (int*)(ws + 222298112);

    detect_mask<<<1, 256, 0, stream>>>((const unsigned char*)mask_ih, flag);

    cast_f32_bf16<<<4096, 256, 0, stream>>>(x, Xb, B * IN);
    mask_cast<<<1024, 256, 0, stream>>>(w_ih, mask_ih, flag, Wih, HID * IN);
    mask_cast<<<256, 256, 0, stream>>>(w_hc, mask_hc, flag, Whc, CNV * HID);

    // GEMM1: [16384,4096] x [2048,4096]^T -> bf16 h ; 64 by x 8 bx = 512 blocks.
    // by in low 3 bits: same-A-panel blocks land on one XCD (r0-measured 270MB).
    gemm256<unsigned short, false><<<512, 512, 0, stream>>>(
        Xb, Wih, b_ih, Hb, nullptr, nullptr, nullptr, nullptr, HID, IN, 3);

    // GEMM2 + fused double conv: [16384,2048] x [1024,2048]^T -> fp32 [16384,256]
    // 64 by x 4 bx = 256 blocks (1 per CU).
    gemm256<float, true><<<256, 512, 0, stream>>>(
        Hb, Whc, b_hc, out, w_c1, b_c1, w_c2, b_c2, CNV, HID, 2);
}